// Round 1
// baseline (144.230 us; speedup 1.0000x reference)
//
#include <hip/hip_runtime.h>

#define BB 4
#define LL 1024
#define DD 1024
#define HH 16
#define HDD 64

typedef __bf16 bf16x8 __attribute__((ext_vector_type(8)));
typedef float f32x4 __attribute__((ext_vector_type(4)));
typedef unsigned short u16x8 __attribute__((ext_vector_type(8)));

__device__ __forceinline__ unsigned short f2bf(float f) {
    unsigned int u = __builtin_bit_cast(unsigned int, f);
    u += 0x7FFFu + ((u >> 16) & 1u);
    return (unsigned short)(u >> 16);
}

// ---------------- prep: x fp32 -> bf16 ----------------
__global__ __launch_bounds__(256) void cvt_x(const float* __restrict__ x,
                                             unsigned short* __restrict__ xb) {
    const int i = (blockIdx.x * 256 + threadIdx.x) * 8;
    f32x4 a0 = *(const f32x4*)(x + i);
    f32x4 a1 = *(const f32x4*)(x + i + 4);
    u16x8 o;
#pragma unroll
    for (int j = 0; j < 4; ++j) { o[j] = f2bf(a0[j]); o[4 + j] = f2bf(a1[j]); }
    *(u16x8*)(xb + i) = o;
}

// ---------------- prep: W (K-major) -> W^T bf16 (N-major) ----------------
__global__ __launch_bounds__(256) void trans_w(const float* __restrict__ Wq,
                                               const float* __restrict__ Wk,
                                               const float* __restrict__ Wv,
                                               const float* __restrict__ Wo,
                                               unsigned short* __restrict__ Wqkv_t,
                                               unsigned short* __restrict__ Wo_t) {
    __shared__ unsigned short lds[64 * 72];
    const int t = threadIdx.x;
    const int mat = blockIdx.z;
    const float* W = (mat == 0) ? Wq : (mat == 1) ? Wk : (mat == 2) ? Wv : Wo;
    unsigned short* out = (mat < 3) ? (Wqkv_t + (size_t)mat * 1024 * 1024) : Wo_t;
    const int k0 = blockIdx.x * 64;
    const int n0 = blockIdx.y * 64;
#pragma unroll
    for (int p = 0; p < 4; ++p) {
        int c = t + p * 256;
        int kr = c >> 4, c4 = (c & 15) * 4;
        f32x4 v = *(const f32x4*)(W + (size_t)(k0 + kr) * 1024 + n0 + c4);
#pragma unroll
        for (int i = 0; i < 4; ++i) lds[(c4 + i) * 72 + kr] = f2bf(v[i]);
    }
    __syncthreads();
#pragma unroll
    for (int p = 0; p < 2; ++p) {
        int c = t + p * 256;
        int nr = c >> 3, koff = (c & 7) * 8;
        u16x8 vv = *(const u16x8*)&lds[nr * 72 + koff];
        *(u16x8*)(out + (size_t)(n0 + nr) * 1024 + k0 + koff) = vv;
    }
}

// ---------------- QKV GEMM: [4096x1024] x [1024x3072] -> qkv heads ----------------
__global__ __launch_bounds__(256) void gemm_qkv(const unsigned short* __restrict__ Abf,
                                                const unsigned short* __restrict__ Btw,
                                                const float* __restrict__ bq,
                                                const float* __restrict__ bk,
                                                const float* __restrict__ bv,
                                                unsigned short* __restrict__ qkv) {
    __shared__ unsigned short Asm[128 * 32];
    __shared__ unsigned short Bsm[128 * 32];
    const int t = threadIdx.x;
    const int w = t >> 6, lane = t & 63;
    const int wm = w >> 1, wn = w & 1;
    const int lr = lane & 15, lk = (lane >> 4) * 8;
    const int row0 = blockIdx.x * 128;
    const int col0 = blockIdx.y * 128;
    const int r = t >> 2;
    const int cb8 = (t & 3) * 8;

    f32x4 acc[4][4];
#pragma unroll
    for (int mf = 0; mf < 4; ++mf)
#pragma unroll
        for (int nf = 0; nf < 4; ++nf)
#pragma unroll
            for (int e = 0; e < 4; ++e) acc[mf][nf][e] = 0.f;

    for (int kt = 0; kt < 32; ++kt) {
        __syncthreads();
        const int k0 = kt * 32;
#pragma unroll
        for (int p = 0; p < 2; ++p) {
            const unsigned short* sa = Abf + (size_t)(row0 + p * 64 + r) * 1024 + k0 + cb8;
            __builtin_amdgcn_global_load_lds(
                (const __attribute__((address_space(1))) unsigned int*)sa,
                (__attribute__((address_space(3))) unsigned int*)(Asm + p * 2048 + t * 8), 16, 0, 0);
            const unsigned short* sb = Btw + (size_t)(col0 + p * 64 + r) * 1024 + k0 + cb8;
            __builtin_amdgcn_global_load_lds(
                (const __attribute__((address_space(1))) unsigned int*)sb,
                (__attribute__((address_space(3))) unsigned int*)(Bsm + p * 2048 + t * 8), 16, 0, 0);
        }
        __syncthreads();
        bf16x8 af[4], bfr[4];
#pragma unroll
        for (int mf = 0; mf < 4; ++mf)
            af[mf] = *(const bf16x8*)&Asm[(wm * 64 + mf * 16 + lr) * 32 + lk];
#pragma unroll
        for (int nf = 0; nf < 4; ++nf)
            bfr[nf] = *(const bf16x8*)&Bsm[(wn * 64 + nf * 16 + lr) * 32 + lk];
#pragma unroll
        for (int mf = 0; mf < 4; ++mf)
#pragma unroll
            for (int nf = 0; nf < 4; ++nf)
                acc[mf][nf] = __builtin_amdgcn_mfma_f32_16x16x32_bf16(af[mf], bfr[nf], acc[mf][nf], 0, 0, 0);
    }

#pragma unroll
    for (int mf = 0; mf < 4; ++mf) {
        const int grow = row0 + wm * 64 + mf * 16 + (lane >> 4) * 4;
#pragma unroll
        for (int nf = 0; nf < 4; ++nf) {
            const int gcol = col0 + wn * 64 + nf * 16 + lr;
            const int mat = gcol >> 10;
            const int nc_ = gcol & 1023;
            const float bias = (mat == 0) ? bq[nc_] : (mat == 1 ? bk[nc_] : bv[nc_]);
            const float scale = (mat == 0) ? 0.125f : 1.0f;
            const int hh = nc_ >> 6, hd = nc_ & 63;
#pragma unroll
            for (int rr = 0; rr < 4; ++rr) {
                const int row = grow + rr;
                const int bb = row >> 10, ll = row & 1023;
                const float vout = (acc[mf][nf][rr] + bias) * scale;
                qkv[((((size_t)mat * BB + bb) * HH + hh) * LL + ll) * HDD + hd] = f2bf(vout);
            }
        }
    }
}

// ---------------- V transpose per head: [L][64] -> [64][L] ----------------
__global__ __launch_bounds__(256) void vtrans(const unsigned short* __restrict__ Vg,
                                              unsigned short* __restrict__ Vt) {
    __shared__ unsigned short lds[64 * 72];
    const int t = threadIdx.x;
    const int bh = blockIdx.y;
    const int j0 = blockIdx.x * 64;
    const size_t hoff = (size_t)bh * LL * HDD;
#pragma unroll
    for (int p = 0; p < 2; ++p) {
        int c = t + p * 256;
        int jr = c >> 3, doff = (c & 7) * 8;
        u16x8 v = *(const u16x8*)(Vg + hoff + (size_t)(j0 + jr) * 64 + doff);
#pragma unroll
        for (int i = 0; i < 8; ++i) lds[(doff + i) * 72 + jr] = v[i];
    }
    __syncthreads();
#pragma unroll
    for (int p = 0; p < 2; ++p) {
        int c = t + p * 256;
        int dr = c >> 3, joff = (c & 7) * 8;
        u16x8 vv = *(const u16x8*)&lds[dr * 72 + joff];
        *(u16x8*)(Vt + hoff + (size_t)dr * 1024 + j0 + joff) = vv;
    }
}

// ---------------- attention: flash-style, 64 q-rows/block, 4 waves ----------------
__global__ __launch_bounds__(256) void attn_kernel(const unsigned short* __restrict__ Qg,
                                                   const unsigned short* __restrict__ Kg,
                                                   const unsigned short* __restrict__ Vtg,
                                                   const int* __restrict__ cid,
                                                   const int* __restrict__ vmask,
                                                   const float* __restrict__ case_bias,
                                                   const float* __restrict__ verb_bias,
                                                   unsigned short* __restrict__ att) {
    __shared__ unsigned short Klds[64 * 72];
    __shared__ unsigned short Vlds[64 * 72];
    __shared__ unsigned short Plds[4][16 * 72];
    __shared__ float caselds[64];
    __shared__ int cidjlds[64];
    __shared__ float vbjlds[64];

    const int t = threadIdx.x;
    const int w = t >> 6;
    const int lane = t & 63;
    const int lr = lane & 15;
    const int lk = (lane >> 4) * 8;

    const int bh = blockIdx.y;
    const int b = bh >> 4;
    const int h = bh & 15;
    const int q0 = blockIdx.x * 64;
    const size_t headoff = (size_t)bh * LL * HDD;

    if (t < 64) caselds[t] = case_bias[h * 64 + t];
    const float vbh = verb_bias[h];

    bf16x8 aq[2];
    {
        const unsigned short* qp = Qg + headoff + (size_t)(q0 + w * 16 + lr) * 64 + lk;
        aq[0] = *(const bf16x8*)(qp);
        aq[1] = *(const bf16x8*)(qp + 32);
    }
    int cbrow[4];
#pragma unroll
    for (int rr = 0; rr < 4; ++rr)
        cbrow[rr] = cid[b * LL + q0 + w * 16 + (lane >> 4) * 4 + rr] * 8;

    float m_run[4], l_run[4];
    f32x4 acc[4];
#pragma unroll
    for (int rr = 0; rr < 4; ++rr) { m_run[rr] = -1e30f; l_run[rr] = 0.f; }
#pragma unroll
    for (int df = 0; df < 4; ++df)
#pragma unroll
        for (int e = 0; e < 4; ++e) acc[df][e] = 0.f;

    const float LOG2E = 1.4426950408889634f;

    for (int jt = 0; jt < 16; ++jt) {
        const int j0 = jt * 64;
        __syncthreads();
#pragma unroll
        for (int p = 0; p < 2; ++p) {
            int c = t + p * 256;
            int row = c >> 3, off = (c & 7) * 8;
            u16x8 kv = *(const u16x8*)(Kg + headoff + (size_t)(j0 + row) * 64 + off);
            *(u16x8*)&Klds[row * 72 + off] = kv;
            u16x8 vv = *(const u16x8*)(Vtg + headoff + (size_t)row * 1024 + j0 + off);
            *(u16x8*)&Vlds[row * 72 + off] = vv;
        }
        if (t < 64) {
            int j = j0 + t;
            cidjlds[t] = cid[b * LL + j];
            vbjlds[t] = vmask[b * LL + j] ? vbh : 0.f;
        }
        __syncthreads();

        f32x4 s[4];
#pragma unroll
        for (int cf = 0; cf < 4; ++cf) {
            f32x4 acc_s;
#pragma unroll
            for (int e = 0; e < 4; ++e) acc_s[e] = 0.f;
#pragma unroll
            for (int ks = 0; ks < 2; ++ks) {
                bf16x8 bk = *(const bf16x8*)&Klds[(cf * 16 + lr) * 72 + ks * 32 + lk];
                acc_s = __builtin_amdgcn_mfma_f32_16x16x32_bf16(aq[ks], bk, acc_s, 0, 0, 0);
            }
            const int jj = cf * 16 + lr;
            const float colb = vbjlds[jj];
            const int cj = cidjlds[jj];
#pragma unroll
            for (int rr = 0; rr < 4; ++rr)
                s[cf][rr] = acc_s[rr] + colb + caselds[cbrow[rr] + cj];
        }

        float sc[4];
#pragma unroll
        for (int rr = 0; rr < 4; ++rr) {
            float v = fmaxf(fmaxf(s[0][rr], s[1][rr]), fmaxf(s[2][rr], s[3][rr]));
            v = fmaxf(v, __shfl_xor(v, 1));
            v = fmaxf(v, __shfl_xor(v, 2));
            v = fmaxf(v, __shfl_xor(v, 4));
            v = fmaxf(v, __shfl_xor(v, 8));
            const float mnew = fmaxf(m_run[rr], v);
            sc[rr] = __builtin_amdgcn_exp2f((m_run[rr] - mnew) * LOG2E);
            m_run[rr] = mnew;
        }
#pragma unroll
        for (int cf = 0; cf < 4; ++cf)
#pragma unroll
            for (int rr = 0; rr < 4; ++rr)
                s[cf][rr] = __builtin_amdgcn_exp2f((s[cf][rr] - m_run[rr]) * LOG2E);
#pragma unroll
        for (int rr = 0; rr < 4; ++rr) {
            float rsv = s[0][rr] + s[1][rr] + s[2][rr] + s[3][rr];
            rsv += __shfl_xor(rsv, 1);
            rsv += __shfl_xor(rsv, 2);
            rsv += __shfl_xor(rsv, 4);
            rsv += __shfl_xor(rsv, 8);
            l_run[rr] = l_run[rr] * sc[rr] + rsv;
        }
#pragma unroll
        for (int df = 0; df < 4; ++df)
#pragma unroll
            for (int rr = 0; rr < 4; ++rr) acc[df][rr] *= sc[rr];

#pragma unroll
        for (int cf = 0; cf < 4; ++cf)
#pragma unroll
            for (int rr = 0; rr < 4; ++rr)
                Plds[w][((lane >> 4) * 4 + rr) * 72 + cf * 16 + lr] = f2bf(s[cf][rr]);
        __syncthreads();

#pragma unroll
        for (int ks = 0; ks < 2; ++ks) {
            bf16x8 ap = *(const bf16x8*)&Plds[w][lr * 72 + ks * 32 + lk];
#pragma unroll
            for (int df = 0; df < 4; ++df) {
                bf16x8 bv = *(const bf16x8*)&Vlds[(df * 16 + lr) * 72 + ks * 32 + lk];
                acc[df] = __builtin_amdgcn_mfma_f32_16x16x32_bf16(ap, bv, acc[df], 0, 0, 0);
            }
        }
    }

#pragma unroll
    for (int rr = 0; rr < 4; ++rr) {
        const float inv = 1.0f / l_run[rr];
        const int grow = q0 + w * 16 + (lane >> 4) * 4 + rr;
        unsigned short* dst = att + (size_t)(b * LL + grow) * DD + h * 64;
#pragma unroll
        for (int df = 0; df < 4; ++df) dst[df * 16 + lr] = f2bf(acc[df][rr] * inv);
    }
}

// ---------------- out GEMM: att[4096x1024] x Wo -> fp32 out ----------------
__global__ __launch_bounds__(256) void gemm_out(const unsigned short* __restrict__ Abf,
                                                const unsigned short* __restrict__ Btw,
                                                const float* __restrict__ bo,
                                                float* __restrict__ out) {
    __shared__ unsigned short Asm[128 * 32];
    __shared__ unsigned short Bsm[128 * 32];
    const int t = threadIdx.x;
    const int w = t >> 6, lane = t & 63;
    const int wm = w >> 1, wn = w & 1;
    const int lr = lane & 15, lk = (lane >> 4) * 8;
    const int row0 = blockIdx.x * 128;
    const int col0 = blockIdx.y * 128;
    const int r = t >> 2;
    const int cb8 = (t & 3) * 8;

    f32x4 acc[4][4];
#pragma unroll
    for (int mf = 0; mf < 4; ++mf)
#pragma unroll
        for (int nf = 0; nf < 4; ++nf)
#pragma unroll
            for (int e = 0; e < 4; ++e) acc[mf][nf][e] = 0.f;

    for (int kt = 0; kt < 32; ++kt) {
        __syncthreads();
        const int k0 = kt * 32;
#pragma unroll
        for (int p = 0; p < 2; ++p) {
            const unsigned short* sa = Abf + (size_t)(row0 + p * 64 + r) * 1024 + k0 + cb8;
            __builtin_amdgcn_global_load_lds(
                (const __attribute__((address_space(1))) unsigned int*)sa,
                (__attribute__((address_space(3))) unsigned int*)(Asm + p * 2048 + t * 8), 16, 0, 0);
            const unsigned short* sb = Btw + (size_t)(col0 + p * 64 + r) * 1024 + k0 + cb8;
            __builtin_amdgcn_global_load_lds(
                (const __attribute__((address_space(1))) unsigned int*)sb,
                (__attribute__((address_space(3))) unsigned int*)(Bsm + p * 2048 + t * 8), 16, 0, 0);
        }
        __syncthreads();
        bf16x8 af[4], bfr[4];
#pragma unroll
        for (int mf = 0; mf < 4; ++mf)
            af[mf] = *(const bf16x8*)&Asm[(wm * 64 + mf * 16 + lr) * 32 + lk];
#pragma unroll
        for (int nf = 0; nf < 4; ++nf)
            bfr[nf] = *(const bf16x8*)&Bsm[(wn * 64 + nf * 16 + lr) * 32 + lk];
#pragma unroll
        for (int mf = 0; mf < 4; ++mf)
#pragma unroll
            for (int nf = 0; nf < 4; ++nf)
                acc[mf][nf] = __builtin_amdgcn_mfma_f32_16x16x32_bf16(af[mf], bfr[nf], acc[mf][nf], 0, 0, 0);
    }

#pragma unroll
    for (int mf = 0; mf < 4; ++mf) {
        const int grow = row0 + wm * 64 + mf * 16 + (lane >> 4) * 4;
#pragma unroll
        for (int nf = 0; nf < 4; ++nf) {
            const int gcol = col0 + wn * 64 + nf * 16 + lr;
            const float bias = bo[gcol];
#pragma unroll
            for (int rr = 0; rr < 4; ++rr)
                out[(size_t)(grow + rr) * 1024 + gcol] = acc[mf][nf][rr] + bias;
        }
    }
}

extern "C" void kernel_launch(void* const* d_in, const int* in_sizes, int n_in,
                              void* d_out, int out_size, void* d_ws, size_t ws_size,
                              hipStream_t stream) {
    const float* x = (const float*)d_in[0];
    const int* cid = (const int*)d_in[1];
    const int* vmask = (const int*)d_in[2];
    const float* Wq = (const float*)d_in[3];
    const float* bq = (const float*)d_in[4];
    const float* Wk = (const float*)d_in[5];
    const float* bk = (const float*)d_in[6];
    const float* Wv = (const float*)d_in[7];
    const float* bv = (const float*)d_in[8];
    const float* Wo = (const float*)d_in[9];
    const float* bo = (const float*)d_in[10];
    const float* case_bias = (const float*)d_in[11];
    const float* verb_bias = (const float*)d_in[12];
    float* out = (float*)d_out;

    char* ws = (char*)d_ws;
    unsigned short* xb     = (unsigned short*)(ws);                       // 8 MB
    unsigned short* Wqkv_t = (unsigned short*)(ws + ((size_t)8 << 20));   // 6 MB
    unsigned short* Wo_t   = (unsigned short*)(ws + ((size_t)14 << 20));  // 2 MB
    unsigned short* qkv    = (unsigned short*)(ws + ((size_t)16 << 20));  // 24 MB
    unsigned short* Vt     = (unsigned short*)(ws + ((size_t)40 << 20));  // 8 MB
    unsigned short* att    = (unsigned short*)(ws + ((size_t)48 << 20));  // 8 MB

    const size_t MATSZ = (size_t)BB * HH * LL * HDD;  // 4 Mi elements

    hipLaunchKernelGGL(cvt_x, dim3(2048), dim3(256), 0, stream, x, xb);
    hipLaunchKernelGGL(trans_w, dim3(16, 16, 4), dim3(256), 0, stream, Wq, Wk, Wv, Wo, Wqkv_t, Wo_t);
    hipLaunchKernelGGL(gemm_qkv, dim3(32, 24), dim3(256), 0, stream, xb, Wqkv_t, bq, bk, bv, qkv);
    hipLaunchKernelGGL(vtrans, dim3(16, 64), dim3(256), 0, stream, qkv + 2 * MATSZ, Vt);
    hipLaunchKernelGGL(attn_kernel, dim3(16, 64), dim3(256), 0, stream,
                       qkv, qkv + MATSZ, Vt, cid, vmask, case_bias, verb_bias, att);
    hipLaunchKernelGGL(gemm_out, dim3(32, 8), dim3(256), 0, stream, att, Wo_t, bo, out);
}

// Round 3
// 108.488 us; speedup vs baseline: 1.3295x; 1.3295x over previous
//
#include <hip/hip_runtime.h>

#define BB 4
#define LL 1024
#define DD 1024
#define HH 16
#define HDD 64

typedef __bf16 bf16x8 __attribute__((ext_vector_type(8)));
typedef float f32x4 __attribute__((ext_vector_type(4)));
typedef float f32x16 __attribute__((ext_vector_type(16)));
typedef unsigned short u16x8 __attribute__((ext_vector_type(8)));
typedef unsigned short u16x4 __attribute__((ext_vector_type(4)));
typedef unsigned int u32x4v __attribute__((ext_vector_type(4)));
typedef unsigned int u32x2 __attribute__((ext_vector_type(2)));

#define LOG2E 1.4426950408889634f

__device__ __forceinline__ unsigned short f2bf(float f) {
    unsigned int u = __builtin_bit_cast(unsigned int, f);
    u += 0x7FFFu + ((u >> 16) & 1u);
    return (unsigned short)(u >> 16);
}

__device__ __forceinline__ unsigned int cvtpk_bf16(float lo, float hi) {
    unsigned int r;
    asm("v_cvt_pk_bf16_f32 %0, %1, %2" : "=v"(r) : "v"(lo), "v"(hi));
    return r;
}

// ---------------- prep: x fp32 -> bf16 ----------------
__global__ __launch_bounds__(256) void cvt_x(const float* __restrict__ x,
                                             unsigned short* __restrict__ xb) {
    const int i = (blockIdx.x * 256 + threadIdx.x) * 8;
    f32x4 a0 = *(const f32x4*)(x + i);
    f32x4 a1 = *(const f32x4*)(x + i + 4);
    u16x8 o;
#pragma unroll
    for (int j = 0; j < 4; ++j) { o[j] = f2bf(a0[j]); o[4 + j] = f2bf(a1[j]); }
    *(u16x8*)(xb + i) = o;
}

// ---------------- prep: W (K-major) -> W^T bf16 (N-major) ----------------
__global__ __launch_bounds__(256) void trans_w(const float* __restrict__ Wq,
                                               const float* __restrict__ Wk,
                                               const float* __restrict__ Wv,
                                               const float* __restrict__ Wo,
                                               unsigned short* __restrict__ Wqkv_t,
                                               unsigned short* __restrict__ Wo_t) {
    __shared__ unsigned short lds[64 * 72];
    const int t = threadIdx.x;
    const int mat = blockIdx.z;
    const float* W = (mat == 0) ? Wq : (mat == 1) ? Wk : (mat == 2) ? Wv : Wo;
    unsigned short* out = (mat < 3) ? (Wqkv_t + (size_t)mat * 1024 * 1024) : Wo_t;
    const int k0 = blockIdx.x * 64;
    const int n0 = blockIdx.y * 64;
#pragma unroll
    for (int p = 0; p < 4; ++p) {
        int c = t + p * 256;
        int kr = c >> 4, c4 = (c & 15) * 4;
        f32x4 v = *(const f32x4*)(W + (size_t)(k0 + kr) * 1024 + n0 + c4);
#pragma unroll
        for (int i = 0; i < 4; ++i) lds[(c4 + i) * 72 + kr] = f2bf(v[i]);
    }
    __syncthreads();
#pragma unroll
    for (int p = 0; p < 2; ++p) {
        int c = t + p * 256;
        int nr = c >> 3, koff = (c & 7) * 8;
        u16x8 vv = *(const u16x8*)&lds[nr * 72 + koff];
        *(u16x8*)(out + (size_t)(n0 + nr) * 1024 + k0 + koff) = vv;
    }
}

// ---------------- QKV GEMM ----------------
__global__ __launch_bounds__(256) void gemm_qkv(const unsigned short* __restrict__ Abf,
                                                const unsigned short* __restrict__ Btw,
                                                const float* __restrict__ bq,
                                                const float* __restrict__ bk,
                                                const float* __restrict__ bv,
                                                unsigned short* __restrict__ qkv) {
    __shared__ unsigned short Asm[128 * 32];
    __shared__ unsigned short Bsm[128 * 32];
    const int t = threadIdx.x;
    const int w = t >> 6, lane = t & 63;
    const int wm = w >> 1, wn = w & 1;
    const int lr = lane & 15, lk = (lane >> 4) * 8;
    const int row0 = blockIdx.x * 128;
    const int col0 = blockIdx.y * 128;
    const int r = t >> 2;
    const int cb8 = (t & 3) * 8;

    f32x4 acc[4][4];
#pragma unroll
    for (int mf = 0; mf < 4; ++mf)
#pragma unroll
        for (int nf = 0; nf < 4; ++nf)
#pragma unroll
            for (int e = 0; e < 4; ++e) acc[mf][nf][e] = 0.f;

    for (int kt = 0; kt < 32; ++kt) {
        __syncthreads();
        const int k0 = kt * 32;
#pragma unroll
        for (int p = 0; p < 2; ++p) {
            const unsigned short* sa = Abf + (size_t)(row0 + p * 64 + r) * 1024 + k0 + cb8;
            __builtin_amdgcn_global_load_lds(
                (const __attribute__((address_space(1))) unsigned int*)sa,
                (__attribute__((address_space(3))) unsigned int*)(Asm + p * 2048 + t * 8), 16, 0, 0);
            const unsigned short* sb = Btw + (size_t)(col0 + p * 64 + r) * 1024 + k0 + cb8;
            __builtin_amdgcn_global_load_lds(
                (const __attribute__((address_space(1))) unsigned int*)sb,
                (__attribute__((address_space(3))) unsigned int*)(Bsm + p * 2048 + t * 8), 16, 0, 0);
        }
        __syncthreads();
        bf16x8 af[4], bfr[4];
#pragma unroll
        for (int mf = 0; mf < 4; ++mf)
            af[mf] = *(const bf16x8*)&Asm[(wm * 64 + mf * 16 + lr) * 32 + lk];
#pragma unroll
        for (int nf = 0; nf < 4; ++nf)
            bfr[nf] = *(const bf16x8*)&Bsm[(wn * 64 + nf * 16 + lr) * 32 + lk];
#pragma unroll
        for (int mf = 0; mf < 4; ++mf)
#pragma unroll
            for (int nf = 0; nf < 4; ++nf)
                acc[mf][nf] = __builtin_amdgcn_mfma_f32_16x16x32_bf16(af[mf], bfr[nf], acc[mf][nf], 0, 0, 0);
    }

#pragma unroll
    for (int mf = 0; mf < 4; ++mf) {
        const int grow = row0 + wm * 64 + mf * 16 + (lane >> 4) * 4;
#pragma unroll
        for (int nf = 0; nf < 4; ++nf) {
            const int gcol = col0 + wn * 64 + nf * 16 + lr;
            const int mat = gcol >> 10;
            const int nc_ = gcol & 1023;
            const float bias = (mat == 0) ? bq[nc_] : (mat == 1 ? bk[nc_] : bv[nc_]);
            // fold 1/sqrt(HD) and LOG2E into Q so attention scores are in log2 units
            const float scale = (mat == 0) ? 0.125f * LOG2E : 1.0f;
            const int hh = nc_ >> 6, hd = nc_ & 63;
#pragma unroll
            for (int rr = 0; rr < 4; ++rr) {
                const int row = grow + rr;
                const int bb = row >> 10, ll = row & 1023;
                const float vout = (acc[mf][nf][rr] + bias) * scale;
                qkv[((((size_t)mat * BB + bb) * HH + hh) * LL + ll) * HDD + hd] = f2bf(vout);
            }
        }
    }
}

// ---------------- V transpose per head: [L][64] -> [64][L] ----------------
__global__ __launch_bounds__(256) void vtrans(const unsigned short* __restrict__ Vg,
                                              unsigned short* __restrict__ Vt) {
    __shared__ unsigned short lds[64 * 72];
    const int t = threadIdx.x;
    const int bh = blockIdx.y;
    const int j0 = blockIdx.x * 64;
    const size_t hoff = (size_t)bh * LL * HDD;
#pragma unroll
    for (int p = 0; p < 2; ++p) {
        int c = t + p * 256;
        int jr = c >> 3, doff = (c & 7) * 8;
        u16x8 v = *(const u16x8*)(Vg + hoff + (size_t)(j0 + jr) * 64 + doff);
#pragma unroll
        for (int i = 0; i < 8; ++i) lds[(doff + i) * 72 + jr] = v[i];
    }
    __syncthreads();
#pragma unroll
    for (int p = 0; p < 2; ++p) {
        int c = t + p * 256;
        int dr = c >> 3, joff = (c & 7) * 8;
        u16x8 vv = *(const u16x8*)&lds[dr * 72 + joff];
        *(u16x8*)(Vt + hoff + (size_t)dr * 1024 + j0 + joff) = vv;
    }
}

// ---------------- attention v2: 32x32 swapped-QK^T, in-register softmax ----------------
// 4 waves/block, each wave owns 32 q-rows (QBLK=128). KVBLK=64, double-buffered LDS.
__global__ __launch_bounds__(256) void attn2(const unsigned short* __restrict__ Qg,
                                             const unsigned short* __restrict__ Kg,
                                             const unsigned short* __restrict__ Vtg,
                                             const int* __restrict__ cid,
                                             const int* __restrict__ vmask,
                                             const float* __restrict__ case_bias,
                                             const float* __restrict__ verb_bias,
                                             unsigned short* __restrict__ att) {
    // per buf: K [64][64] bf16 (swizzled) at offset 0, V^T [64][64] at offset 4096
    __shared__ unsigned short kvbuf[2][8192];
    __shared__ float tbl[2][8][68];  // [buf][ci][j] combined bias * LOG2E, stride 68 kills conflicts

    const int t = threadIdx.x;
    const int w = t >> 6;
    const int lane = t & 63;
    const int q31 = lane & 31;  // q (or j/d row) within 32-tile
    const int g = lane >> 5;

    // XCD-aware decode: all 8 q-tiles of a head on the same XCD (K/V L2-resident)
    const int f = blockIdx.x;
    const int qt = (f >> 3) & 7;
    const int bh = ((f & 7) << 3) | (f >> 6);
    const int b = bh >> 4, h = bh & 15;
    const size_t headoff = (size_t)bh * LL * HDD;
    const int q0 = qt * 128;
    const int qrow = q0 + w * 32 + q31;

    // Q fragments (B-operand): col=lane&31=q, k=g*8+e within each 16-chunk
    bf16x8 qf[4];
    {
        const unsigned short* qp = Qg + headoff + (size_t)qrow * HDD + g * 8;
        qf[0] = *(const bf16x8*)(qp);
        qf[1] = *(const bf16x8*)(qp + 16);
        qf[2] = *(const bf16x8*)(qp + 32);
        qf[3] = *(const bf16x8*)(qp + 48);
    }
    const int cirow = cid[b * LL + qrow] * 68;
    const float vbh = verb_bias[h] * LOG2E;

    float m_run = -1e30f, l_run = 0.f;
    f32x16 acc0, acc1;
#pragma unroll
    for (int e = 0; e < 16; ++e) { acc0[e] = 0.f; acc1[e] = 0.f; }

    const int r8 = lane >> 3, c8 = lane & 7;

#define STAGE(bufn, j0)                                                                            \
    {                                                                                              \
        _Pragma("unroll") for (int cc = 0; cc < 2; ++cc) {                                         \
            const int chunk = w + cc * 4;                                                          \
            const int row = chunk * 8 + r8;                                                        \
            const int sc8 = (c8 ^ (row & 7)) * 8;                                                  \
            const unsigned short* srck = Kg + headoff + (size_t)((j0) + row) * HDD + sc8;          \
            __builtin_amdgcn_global_load_lds(                                                      \
                (const __attribute__((address_space(1))) unsigned int*)srck,                       \
                (__attribute__((address_space(3))) unsigned int*)(&kvbuf[bufn][chunk * 512]), 16,  \
                0, 0);                                                                             \
            const unsigned short* srcv = Vtg + headoff + (size_t)row * LL + (j0) + sc8;            \
            __builtin_amdgcn_global_load_lds(                                                      \
                (const __attribute__((address_space(1))) unsigned int*)srcv,                       \
                (__attribute__((address_space(3))) unsigned int*)(&kvbuf[bufn][4096 + chunk * 512]),\
                16, 0, 0);                                                                         \
        }                                                                                          \
        const int jj = t & 63, ci0 = t >> 6;                                                       \
        const int cj = cid[b * LL + (j0) + jj];                                                    \
        const float vb = vmask[b * LL + (j0) + jj] ? vbh : 0.f;                                    \
        tbl[bufn][ci0][jj] = case_bias[h * 64 + ci0 * 8 + cj] * LOG2E + vb;                        \
        tbl[bufn][ci0 + 4][jj] = case_bias[h * 64 + (ci0 + 4) * 8 + cj] * LOG2E + vb;              \
    }

    STAGE(0, 0);
    __syncthreads();

    for (int jt = 0; jt < 16; ++jt) {
        const int buf = jt & 1;
        if (jt < 15) STAGE(buf ^ 1, (jt + 1) * 64);

        // ---- QK^T (S^T): 2 j-tiles of 32, bias preloaded into accumulator ----
        const float* tb = &tbl[buf][0][0] + cirow + 4 * g;
        f32x16 st[2];
#pragma unroll
        for (int jt2 = 0; jt2 < 2; ++jt2) {
            f32x16 s;
#pragma unroll
            for (int r = 0; r < 16; ++r) s[r] = tb[jt2 * 32 + (r & 3) + 8 * (r >> 2)];
            const int arow = jt2 * 32 + q31;
            const unsigned short* kb = &kvbuf[buf][arow * 64];
            const int swz = arow & 7;
#pragma unroll
            for (int kk = 0; kk < 4; ++kk) {
                bf16x8 af = *(const bf16x8*)&kb[((2 * kk + g) ^ swz) * 8];
                s = __builtin_amdgcn_mfma_f32_32x32x16_bf16(af, qf[kk], s, 0, 0, 0);
            }
            st[jt2] = s;
        }

        // ---- online softmax (log2 units), in-register row reduce ----
        float mx[16];
#pragma unroll
        for (int r = 0; r < 16; ++r) mx[r] = fmaxf(st[0][r], st[1][r]);
#pragma unroll
        for (int d = 8; d >= 1; d >>= 1)
#pragma unroll
            for (int r = 0; r < 8; ++r)
                if (r < d) mx[r] = fmaxf(mx[r], mx[r + d]);
        float tmax = fmaxf(mx[0], __shfl_xor(mx[0], 32));

        if (!__all(tmax <= m_run + 8.f)) {  // defer-max (T13), THR=8 in log2 units
            const float mnew = fmaxf(m_run, tmax);
            const float sc = __builtin_amdgcn_exp2f(m_run - mnew);
            m_run = mnew;
            l_run *= sc;
#pragma unroll
            for (int e = 0; e < 16; ++e) { acc0[e] *= sc; acc1[e] *= sc; }
        }

        float tsum = 0.f;
#pragma unroll
        for (int jt2 = 0; jt2 < 2; ++jt2)
#pragma unroll
            for (int r = 0; r < 16; ++r) {
                const float p = __builtin_amdgcn_exp2f(st[jt2][r] - m_run);
                st[jt2][r] = p;
                tsum += p;
            }
        tsum += __shfl_xor(tsum, 32);
        l_run += tsum;

        // ---- P -> bf16 B-fragments via cvt_pk + permlane32_swap, then PV ----
        // Lane holds p[r]=P^T[j][q] with j=(r&3)+8*(r>>2)+4g (+32*jt2). B-frag for K-slot kk
        // needs word i = (j=16kk+8g+2i, j+1). Derivation: a0=cvtpk(p0,p1), b0=cvtpk(p4,p5);
        // permlane32_swap(a0,b0) -> result0={a0.lo,b0.lo}=word0, result1={a0.hi,b0.hi}=word2.
#pragma unroll
        for (int kk = 0; kk < 4; ++kk) {
            const int jt2 = kk >> 1, rb = (kk & 1) * 8;
            unsigned int a0 = cvtpk_bf16(st[jt2][rb + 0], st[jt2][rb + 1]);
            unsigned int b0 = cvtpk_bf16(st[jt2][rb + 4], st[jt2][rb + 5]);
            unsigned int a1 = cvtpk_bf16(st[jt2][rb + 2], st[jt2][rb + 3]);
            unsigned int b1 = cvtpk_bf16(st[jt2][rb + 6], st[jt2][rb + 7]);
            u32x2 r0 = __builtin_amdgcn_permlane32_swap(a0, b0, false, false);
            u32x2 r1 = __builtin_amdgcn_permlane32_swap(a1, b1, false, false);
            u32x4v pw;
            pw[0] = r0[0]; pw[1] = r1[0]; pw[2] = r0[1]; pw[3] = r1[1];
            const bf16x8 pf = __builtin_bit_cast(bf16x8, pw);
#pragma unroll
            for (int dt = 0; dt < 2; ++dt) {
                const int vrow = dt * 32 + q31;
                const bf16x8 vf =
                    *(const bf16x8*)&kvbuf[buf][4096 + vrow * 64 + (((2 * kk + g) ^ (vrow & 7)) * 8)];
                if (dt == 0)
                    acc0 = __builtin_amdgcn_mfma_f32_32x32x16_bf16(vf, pf, acc0, 0, 0, 0);
                else
                    acc1 = __builtin_amdgcn_mfma_f32_32x32x16_bf16(vf, pf, acc1, 0, 0, 0);
            }
        }
        __syncthreads();
    }

    // ---- epilogue: out^T -> LDS (swizzled) -> coalesced global store ----
    const float inv = 1.0f / l_run;
    unsigned short* ob = &kvbuf[0][0];  // [128][64]
    const int orow = w * 32 + q31;
    const int oswz = (orow & 7) << 3;
#pragma unroll
    for (int dt = 0; dt < 2; ++dt) {
#pragma unroll
        for (int u = 0; u < 4; ++u) {
            u16x4 v4;
#pragma unroll
            for (int v = 0; v < 4; ++v)
                v4[v] = f2bf((dt ? acc1[4 * u + v] : acc0[4 * u + v]) * inv);
            const int d0 = dt * 32 + 8 * u + 4 * g;
            *(u16x4*)&ob[orow * 64 + (d0 ^ oswz)] = v4;
        }
    }
    __syncthreads();
#pragma unroll
    for (int p = 0; p < 4; ++p) {
        const int row = p * 32 + (t >> 3);
        const int c16 = t & 7;
        u16x8 v = *(const u16x8*)&ob[row * 64 + ((c16 ^ (row & 7)) * 8)];
        *(u16x8*)(att + (size_t)(b * LL + q0 + row) * DD + h * 64 + c16 * 8) = v;
    }
#undef STAGE
}

// ---------------- out GEMM: att[4096x1024] x Wo -> fp32 out ----------------
__global__ __launch_bounds__(256) void gemm_out(const unsigned short* __restrict__ Abf,
                                                const unsigned short* __restrict__ Btw,
                                                const float* __restrict__ bo,
                                                float* __restrict__ out) {
    __shared__ unsigned short Asm[128 * 32];
    __shared__ unsigned short Bsm[128 * 32];
    const int t = threadIdx.x;
    const int w = t >> 6, lane = t & 63;
    const int wm = w >> 1, wn = w & 1;
    const int lr = lane & 15, lk = (lane >> 4) * 8;
    const int row0 = blockIdx.x * 128;
    const int col0 = blockIdx.y * 128;
    const int r = t >> 2;
    const int cb8 = (t & 3) * 8;

    f32x4 acc[4][4];
#pragma unroll
    for (int mf = 0; mf < 4; ++mf)
#pragma unroll
        for (int nf = 0; nf < 4; ++nf)
#pragma unroll
            for (int e = 0; e < 4; ++e) acc[mf][nf][e] = 0.f;

    for (int kt = 0; kt < 32; ++kt) {
        __syncthreads();
        const int k0 = kt * 32;
#pragma unroll
        for (int p = 0; p < 2; ++p) {
            const unsigned short* sa = Abf + (size_t)(row0 + p * 64 + r) * 1024 + k0 + cb8;
            __builtin_amdgcn_global_load_lds(
                (const __attribute__((address_space(1))) unsigned int*)sa,
                (__attribute__((address_space(3))) unsigned int*)(Asm + p * 2048 + t * 8), 16, 0, 0);
            const unsigned short* sb = Btw + (size_t)(col0 + p * 64 + r) * 1024 + k0 + cb8;
            __builtin_amdgcn_global_load_lds(
                (const __attribute__((address_space(1))) unsigned int*)sb,
                (__attribute__((address_space(3))) unsigned int*)(Bsm + p * 2048 + t * 8), 16, 0, 0);
        }
        __syncthreads();
        bf16x8 af[4], bfr[4];
#pragma unroll
        for (int mf = 0; mf < 4; ++mf)
            af[mf] = *(const bf16x8*)&Asm[(wm * 64 + mf * 16 + lr) * 32 + lk];
#pragma unroll
        for (int nf = 0; nf < 4; ++nf)
            bfr[nf] = *(const bf16x8*)&Bsm[(wn * 64 + nf * 16 + lr) * 32 + lk];
#pragma unroll
        for (int mf = 0; mf < 4; ++mf)
#pragma unroll
            for (int nf = 0; nf < 4; ++nf)
                acc[mf][nf] = __builtin_amdgcn_mfma_f32_16x16x32_bf16(af[mf], bfr[nf], acc[mf][nf], 0, 0, 0);
    }

#pragma unroll
    for (int mf = 0; mf < 4; ++mf) {
        const int grow = row0 + wm * 64 + mf * 16 + (lane >> 4) * 4;
#pragma unroll
        for (int nf = 0; nf < 4; ++nf) {
            const int gcol = col0 + wn * 64 + nf * 16 + lr;
            const float bias = bo[gcol];
#pragma unroll
            for (int rr = 0; rr < 4; ++rr)
                out[(size_t)(grow + rr) * 1024 + gcol] = acc[mf][nf][rr] + bias;
        }
    }
}

extern "C" void kernel_launch(void* const* d_in, const int* in_sizes, int n_in,
                              void* d_out, int out_size, void* d_ws, size_t ws_size,
                              hipStream_t stream) {
    const float* x = (const float*)d_in[0];
    const int* cid = (const int*)d_in[1];
    const int* vmask = (const int*)d_in[2];
    const float* Wq = (const float*)d_in[3];
    const float* bq = (const float*)d_in[4];
    const float* Wk = (const float*)d_in[5];
    const float* bk = (const float*)d_in[6];
    const float* Wv = (const float*)d_in[7];
    const float* bv = (const float*)d_in[8];
    const float* Wo = (const float*)d_in[9];
    const float* bo = (const float*)d_in[10];
    const float* case_bias = (const float*)d_in[11];
    const float* verb_bias = (const float*)d_in[12];
    float* out = (float*)d_out;

    char* ws = (char*)d_ws;
    unsigned short* xb     = (unsigned short*)(ws);                       // 8 MB
    unsigned short* Wqkv_t = (unsigned short*)(ws + ((size_t)8 << 20));   // 6 MB
    unsigned short* Wo_t   = (unsigned short*)(ws + ((size_t)14 << 20));  // 2 MB
    unsigned short* qkv    = (unsigned short*)(ws + ((size_t)16 << 20));  // 24 MB
    unsigned short* Vt     = (unsigned short*)(ws + ((size_t)40 << 20));  // 8 MB
    unsigned short* att    = (unsigned short*)(ws + ((size_t)48 << 20));  // 8 MB

    const size_t MATSZ = (size_t)BB * HH * LL * HDD;  // 4 Mi elements

    hipLaunchKernelGGL(cvt_x, dim3(2048), dim3(256), 0, stream, x, xb);
    hipLaunchKernelGGL(trans_w, dim3(16, 16, 4), dim3(256), 0, stream, Wq, Wk, Wv, Wo, Wqkv_t, Wo_t);
    hipLaunchKernelGGL(gemm_qkv, dim3(32, 24), dim3(256), 0, stream, xb, Wqkv_t, bq, bk, bv, qkv);
    hipLaunchKernelGGL(vtrans, dim3(16, 64), dim3(256), 0, stream, qkv + 2 * MATSZ, Vt);
    hipLaunchKernelGGL(attn2, dim3(512), dim3(256), 0, stream,
                       qkv, qkv + MATSZ, Vt, cid, vmask, case_bias, verb_bias, att);
    hipLaunchKernelGGL(gemm_out, dim3(32, 8), dim3(256), 0, stream, att, Wo_t, bo, out);
}